// Round 1
// baseline (1648.578 us; speedup 1.0000x reference)
//
#include <hip/hip_runtime.h>
#include <hip/hip_bf16.h>

#define N_NODES 25000
#define N_EDGES 400000
#define N_GRAPHS 1000
#define HID 185

// ---------------- init: deg=1 (self loop), pooled=0 (encoded -inf floor) ----
__global__ void k_init(float* deg, unsigned* pooled, int n, int p) {
    int i = blockIdx.x * blockDim.x + threadIdx.x;
    if (i < n) deg[i] = 1.0f;
    if (i < p) pooled[i] = 0u;
}

__global__ void k_deg(const int* __restrict__ dst, float* deg, int E) {
    int i = blockIdx.x * blockDim.x + threadIdx.x;
    if (i < E) atomicAdd(&deg[dst[i]], 1.0f);
}

__global__ void k_rsqrt_inplace(float* deg, int n) {
    int i = blockIdx.x * blockDim.x + threadIdx.x;
    if (i < n) deg[i] = rsqrtf(deg[i]);
}

// ---------------- GEMM: C[N x 185] = A[N x K] @ W[K x 185] (+bias) ----------
// 8 rows per block, A-tile staged in LDS k-major so inner loop reads the 8
// row values as two b128 LDS loads. W[k*185+c] is cached (reused by every block).
template<int K>
__global__ __launch_bounds__(192) void k_gemm(const float* __restrict__ A, int lda,
                                              const float* __restrict__ W,
                                              const float* __restrict__ bias,
                                              float* __restrict__ C, int N) {
    __shared__ float As[8 * K];
    const int tid = threadIdx.x;
    const int r0 = blockIdx.x * 8;
    for (int idx = tid; idx < 8 * K; idx += 192) {
        int r = idx & 7;
        int k = idx >> 3;
        int row = r0 + r;
        As[idx] = (row < N) ? A[row * lda + k] : 0.0f;
    }
    __syncthreads();
    const int c = tid;
    if (c >= HID) return;
    float acc[8] = {0.f,0.f,0.f,0.f,0.f,0.f,0.f,0.f};
    for (int k = 0; k < K; ++k) {
        float w = W[k * HID + c];
        #pragma unroll
        for (int r = 0; r < 8; ++r)
            acc[r] += As[k * 8 + r] * w;
    }
    float bb = bias ? bias[c] : 0.0f;
    #pragma unroll
    for (int r = 0; r < 8; ++r) {
        int row = r0 + r;
        if (row < N) C[row * HID + c] = acc[r] + bb;
    }
}

// ---------------- aggregation ----------------------------------------------
// self-loop term: aggr[n] = tmp[n] * dis[n]^2
__global__ __launch_bounds__(192) void k_aggr_self(const float* __restrict__ tmp,
                                                   const float* __restrict__ dis,
                                                   float* __restrict__ aggr, int N) {
    int n = blockIdx.x;
    float dn = dis[n];
    int c = threadIdx.x;
    if (c < HID) aggr[n * HID + c] = tmp[n * HID + c] * dn * dn;
}

// edge messages: aggr[dst] += tmp[src] * dis[src]*dis[dst]
#define EDGES_PER_BLOCK 8
__global__ __launch_bounds__(192) void k_aggr_edges(const int* __restrict__ src,
                                                    const int* __restrict__ dst,
                                                    const float* __restrict__ dis,
                                                    const float* __restrict__ tmp,
                                                    float* __restrict__ aggr, int E) {
    int e0 = blockIdx.x * EDGES_PER_BLOCK;
    int c = threadIdx.x;
    #pragma unroll
    for (int i = 0; i < EDGES_PER_BLOCK; ++i) {
        int e = e0 + i;
        if (e >= E) break;
        int s = src[e];       // block-uniform -> scalar loads
        int d = dst[e];
        float en = dis[s] * dis[d];
        if (c < HID) atomicAdd(&aggr[d * HID + c], tmp[s * HID + c] * en);
    }
}

// bias + batchnorm(eval) + relu, write into the JK concat buffer (stride 740)
__global__ __launch_bounds__(192) void k_bn_relu(const float* __restrict__ aggr,
                                                 const float* __restrict__ b,
                                                 const float* __restrict__ gamma,
                                                 const float* __restrict__ beta,
                                                 const float* __restrict__ mean,
                                                 const float* __restrict__ var,
                                                 float* __restrict__ out, int N) {
    int n = blockIdx.x;
    int c = threadIdx.x;
    if (c < HID) {
        float v = aggr[n * HID + c] + b[c];
        v = (v - mean[c]) * rsqrtf(var[c] + 1e-5f) * gamma[c] + beta[c];
        out[n * (4 * HID) + c] = fmaxf(v, 0.0f);
    }
}

// ---------------- global max pool (order-preserving uint encoding) ----------
__global__ __launch_bounds__(192) void k_pool(const float* __restrict__ h,
                                              const int* __restrict__ batch,
                                              unsigned* __restrict__ pooled, int N) {
    int n = blockIdx.x;
    int g = batch[n];          // block-uniform
    int c = threadIdx.x;
    if (c < HID) {
        unsigned b = __float_as_uint(h[n * HID + c]);
        unsigned enc = (b & 0x80000000u) ? ~b : (b | 0x80000000u);
        atomicMax(&pooled[g * HID + c], enc);
    }
}

// out[g] = dot(decode(pooled[g]), W_out) + b_out
__global__ __launch_bounds__(64) void k_out(const unsigned* __restrict__ pooled,
                                            const float* __restrict__ W_out,
                                            const float* __restrict__ b_out,
                                            float* __restrict__ out, int G) {
    int g = blockIdx.x;
    int lane = threadIdx.x;
    float sum = 0.0f;
    for (int c = lane; c < HID; c += 64) {
        unsigned u = pooled[g * HID + c];
        unsigned bits = (u & 0x80000000u) ? (u & 0x7FFFFFFFu) : ~u;
        sum += __uint_as_float(bits) * W_out[c];
    }
    #pragma unroll
    for (int off = 32; off; off >>= 1) sum += __shfl_down(sum, off);
    if (lane == 0) out[g] = sum + b_out[0];
}

extern "C" void kernel_launch(void* const* d_in, const int* in_sizes, int n_in,
                              void* d_out, int out_size, void* d_ws, size_t ws_size,
                              hipStream_t stream) {
    const float* x      = (const float*)d_in[0];
    const int*   ei     = (const int*)  d_in[1];
    const int*   batch  = (const int*)  d_in[2];
    const float* W0     = (const float*)d_in[3];
    const float* b0     = (const float*)d_in[4];
    const float* W_h    = (const float*)d_in[5];
    const float* b_h    = (const float*)d_in[6];
    const float* gamma  = (const float*)d_in[7];
    const float* beta   = (const float*)d_in[8];
    const float* mean   = (const float*)d_in[9];
    const float* var    = (const float*)d_in[10];
    const float* W_jk   = (const float*)d_in[11];
    const float* b_jk   = (const float*)d_in[12];
    const float* W_out  = (const float*)d_in[13];
    const float* b_out  = (const float*)d_in[14];
    float* out = (float*)d_out;

    const int N = N_NODES, E = N_EDGES, G = N_GRAPHS, H = HID;

    // workspace layout (floats), 128B-aligned chunks
    float* ws   = (float*)d_ws;
    float* dis  = ws;                       // 25000   (deg -> rsqrt in place)
    float* tmp  = dis  + 25088;             // 25000*185 = 4,625,000
    float* aggr = tmp  + 4625024;           // 4,625,000
    float* xcat = aggr + 4625024;           // 25000*740 = 18,500,000
    unsigned* pooled = (unsigned*)(xcat + 18500096);  // 1000*185

    const int* src = ei;          // edge_index[0]
    const int* dst = ei + E;      // edge_index[1]

    k_init<<<(G * H + 255) / 256, 256, 0, stream>>>(dis, pooled, N, G * H);
    k_deg<<<(E + 255) / 256, 256, 0, stream>>>(dst, dis, E);
    k_rsqrt_inplace<<<(N + 255) / 256, 256, 0, stream>>>(dis, N);

    for (int l = 0; l < 4; ++l) {
        const float* A   = (l == 0) ? x : (xcat + (l - 1) * H);
        int lda          = (l == 0) ? 9 : 4 * H;
        const float* W   = (l == 0) ? W0 : (W_h + (l - 1) * H * H);
        const float* b   = (l == 0) ? b0 : (b_h + (l - 1) * H);
        if (l == 0)
            k_gemm<9><<<N / 8, 192, 0, stream>>>(A, lda, W, nullptr, tmp, N);
        else
            k_gemm<185><<<N / 8, 192, 0, stream>>>(A, lda, W, nullptr, tmp, N);
        k_aggr_self<<<N, 192, 0, stream>>>(tmp, dis, aggr, N);
        k_aggr_edges<<<(E + EDGES_PER_BLOCK - 1) / EDGES_PER_BLOCK, 192, 0, stream>>>(
            src, dst, dis, tmp, aggr, E);
        k_bn_relu<<<N, 192, 0, stream>>>(aggr, b, gamma + l * H, beta + l * H,
                                         mean + l * H, var + l * H, xcat + l * H, N);
    }

    // JumpingKnowledge cat -> linear (740 -> 185), bias fused
    k_gemm<740><<<N / 8, 192, 0, stream>>>(xcat, 4 * H, W_jk, b_jk, tmp, N);

    k_pool<<<N, 192, 0, stream>>>(tmp, batch, pooled, N);
    k_out<<<G, 64, 0, stream>>>(pooled, W_out, b_out, out, G);
}

// Round 2
// 647.581 us; speedup vs baseline: 2.5457x; 2.5457x over previous
//
#include <hip/hip_runtime.h>
#include <hip/hip_bf16.h>

#define N_NODES 25000
#define N_EDGES 400000
#define N_GRAPHS 1000
#define HID 185
#define EPS 1e-5f

// ---- init: zero int counters (cnt, cursor) and pooled encoding floor -------
__global__ void k_init(int* cnt, int* cursor, unsigned* pooled) {
    int i = blockIdx.x * blockDim.x + threadIdx.x;
    if (i < N_NODES) { cnt[i] = 0; cursor[i] = 0; }
    if (i < N_GRAPHS * HID) pooled[i] = 0u;
}

__global__ void k_deg(const int* __restrict__ dst, int* cnt, int E) {
    int i = blockIdx.x * blockDim.x + threadIdx.x;
    if (i < E) atomicAdd(&cnt[dst[i]], 1);
}

// dis[n] = 1/sqrt(deg) with deg = incoming + 1 (self loop)
__global__ void k_dis(const int* __restrict__ cnt, float* dis, int N) {
    int i = blockIdx.x * blockDim.x + threadIdx.x;
    if (i < N) dis[i] = rsqrtf((float)(cnt[i] + 1));
}

// exclusive prefix sum of cnt[0..N) -> rowptr[0..N], single block of 1024
__global__ __launch_bounds__(1024) void k_scan(const int* __restrict__ cnt,
                                               int* __restrict__ rowptr, int N) {
    __shared__ int s[1024];
    const int tid = threadIdx.x;
    int carry = 0;
    for (int base = 0; base < N; base += 1024) {
        int i = base + tid;
        int v = (i < N) ? cnt[i] : 0;
        s[tid] = v;
        __syncthreads();
        for (int off = 1; off < 1024; off <<= 1) {
            int t = (tid >= off) ? s[tid - off] : 0;
            __syncthreads();
            s[tid] += t;
            __syncthreads();
        }
        int incl = s[tid];
        if (i < N) rowptr[i + 1] = carry + incl;
        int chunk_total = s[1023];
        __syncthreads();
        carry += chunk_total;
    }
    if (tid == 0) rowptr[0] = 0;
}

// bucket edges by dst; also stash dis[src] so the hot loop needs no gather
__global__ void k_scatter(const int* __restrict__ src, const int* __restrict__ dst,
                          const float* __restrict__ dis, const int* __restrict__ rowptr,
                          int* cursor, int* __restrict__ csr_src,
                          float* __restrict__ csr_w, int E) {
    int e = blockIdx.x * blockDim.x + threadIdx.x;
    if (e < E) {
        int d = dst[e];
        int s = src[e];
        int pos = atomicAdd(&cursor[d], 1);
        int o = rowptr[d] + pos;
        csr_src[o] = s;
        csr_w[o] = dis[s];
    }
}

// ---- layer-0 aggregation in 9-channel input space --------------------------
// xa[n] = (x[n]*dis[n] + sum_in x[s]*dis[s]) * dis[n]
__global__ void k_aggr0(const float* __restrict__ x, const float* __restrict__ dis,
                        const int* __restrict__ rowptr, const int* __restrict__ csr_src,
                        const float* __restrict__ csr_w, float* __restrict__ xa, int N) {
    int idx = blockIdx.x * blockDim.x + threadIdx.x;
    int n = idx >> 4;
    int c = idx & 15;
    if (n >= N || c >= 9) return;
    float dn = dis[n];
    float acc = x[n * 9 + c] * dn;
    int beg = rowptr[n], end = rowptr[n + 1];
    for (int e = beg; e < end; ++e)
        acc += x[csr_src[e] * 9 + c] * csr_w[e];
    xa[n * 9 + c] = acc * dn;
}

// ---- GEMM: C[N x 185] = A[N x K] @ W[K x 185], optional bias / BN+ReLU -----
template<int K>
__global__ __launch_bounds__(192) void k_gemm(const float* __restrict__ A, int lda,
                                              const float* __restrict__ W,
                                              const float* __restrict__ bias,
                                              const float* __restrict__ gamma,
                                              const float* __restrict__ beta,
                                              const float* __restrict__ mean,
                                              const float* __restrict__ var,
                                              float* __restrict__ C, int ldc, int N) {
    __shared__ float As[8 * K];
    const int tid = threadIdx.x;
    const int r0 = blockIdx.x * 8;
    for (int idx = tid; idx < 8 * K; idx += 192) {
        int r = idx & 7;
        int k = idx >> 3;
        int row = r0 + r;
        As[idx] = (row < N) ? A[row * lda + k] : 0.0f;
    }
    __syncthreads();
    const int c = tid;
    if (c >= HID) return;
    float acc[8] = {0.f,0.f,0.f,0.f,0.f,0.f,0.f,0.f};
    for (int k = 0; k < K; ++k) {
        float w = W[k * HID + c];
        #pragma unroll
        for (int r = 0; r < 8; ++r)
            acc[r] += As[k * 8 + r] * w;
    }
    float bb = bias ? bias[c] : 0.0f;
    float scale = 1.0f, shift = 0.0f;
    const bool bn = (gamma != nullptr);
    if (bn) {
        scale = rsqrtf(var[c] + EPS) * gamma[c];
        shift = beta[c] - mean[c] * scale;
    }
    #pragma unroll
    for (int r = 0; r < 8; ++r) {
        int row = r0 + r;
        if (row < N) {
            float v = acc[r] + bb;
            if (bn) v = fmaxf(v * scale + shift, 0.0f);
            C[row * ldc + c] = v;
        }
    }
}

// ---- fused aggregation + bias + BN + ReLU (layers 1..3) --------------------
// out[n] = relu(bn( (tmp[n]*dis[n] + sum_in tmp[s]*dis[s]) * dis[n] + b ))
__global__ __launch_bounds__(192) void k_aggr_bn(const float* __restrict__ tmp,
                                                 const float* __restrict__ dis,
                                                 const int* __restrict__ rowptr,
                                                 const int* __restrict__ csr_src,
                                                 const float* __restrict__ csr_w,
                                                 const float* __restrict__ b,
                                                 const float* __restrict__ gamma,
                                                 const float* __restrict__ beta,
                                                 const float* __restrict__ mean,
                                                 const float* __restrict__ var,
                                                 float* __restrict__ out, int N) {
    int n = blockIdx.x;
    int c = threadIdx.x;
    if (c >= HID) return;
    int beg = rowptr[n], end = rowptr[n + 1];
    float dn = dis[n];
    float acc = tmp[n * HID + c] * dn;
    int e = beg;
    for (; e + 1 < end; e += 2) {
        int s0 = csr_src[e];
        int s1 = csr_src[e + 1];
        float w0 = csr_w[e];
        float w1 = csr_w[e + 1];
        float v0 = tmp[s0 * HID + c];
        float v1 = tmp[s1 * HID + c];
        acc += v0 * w0;
        acc += v1 * w1;
    }
    if (e < end)
        acc += tmp[csr_src[e] * HID + c] * csr_w[e];
    acc = acc * dn + b[c];
    float scale = rsqrtf(var[c] + EPS) * gamma[c];
    float v = (acc - mean[c]) * scale + beta[c];
    out[n * (4 * HID) + c] = fmaxf(v, 0.0f);
}

// ---- global max pool (order-preserving uint encoding) ----------------------
__global__ __launch_bounds__(192) void k_pool(const float* __restrict__ h,
                                              const int* __restrict__ batch,
                                              unsigned* __restrict__ pooled, int N) {
    int n = blockIdx.x;
    int g = batch[n];
    int c = threadIdx.x;
    if (c < HID) {
        unsigned b = __float_as_uint(h[n * HID + c]);
        unsigned enc = (b & 0x80000000u) ? ~b : (b | 0x80000000u);
        atomicMax(&pooled[g * HID + c], enc);
    }
}

__global__ __launch_bounds__(64) void k_out(const unsigned* __restrict__ pooled,
                                            const float* __restrict__ W_out,
                                            const float* __restrict__ b_out,
                                            float* __restrict__ out, int G) {
    int g = blockIdx.x;
    int lane = threadIdx.x;
    float sum = 0.0f;
    for (int c = lane; c < HID; c += 64) {
        unsigned u = pooled[g * HID + c];
        unsigned bits = (u & 0x80000000u) ? (u & 0x7FFFFFFFu) : ~u;
        sum += __uint_as_float(bits) * W_out[c];
    }
    #pragma unroll
    for (int off = 32; off; off >>= 1) sum += __shfl_down(sum, off);
    if (lane == 0) out[g] = sum + b_out[0];
}

extern "C" void kernel_launch(void* const* d_in, const int* in_sizes, int n_in,
                              void* d_out, int out_size, void* d_ws, size_t ws_size,
                              hipStream_t stream) {
    const float* x      = (const float*)d_in[0];
    const int*   ei     = (const int*)  d_in[1];
    const int*   batch  = (const int*)  d_in[2];
    const float* W0     = (const float*)d_in[3];
    const float* b0     = (const float*)d_in[4];
    const float* W_h    = (const float*)d_in[5];
    const float* b_h    = (const float*)d_in[6];
    const float* gamma  = (const float*)d_in[7];
    const float* beta   = (const float*)d_in[8];
    const float* mean   = (const float*)d_in[9];
    const float* var    = (const float*)d_in[10];
    const float* W_jk   = (const float*)d_in[11];
    const float* b_jk   = (const float*)d_in[12];
    const float* W_out  = (const float*)d_in[13];
    const float* b_out  = (const float*)d_in[14];
    float* out = (float*)d_out;

    const int N = N_NODES, E = N_EDGES, G = N_GRAPHS, H = HID;

    // workspace layout (float-sized slots, 128B-aligned chunks)
    float* ws   = (float*)d_ws;
    float* dis  = ws;                        // 25,000
    float* xa   = dis  + 25088;              // 25,000*9   = 225,000
    float* tmp  = xa   + 225024 + 8;         // 25,000*185 = 4,625,000
    float* xcat = tmp  + 4625024;            // 25,000*740 = 18,500,000
    float* csr_w = xcat + 18500096;          // 400,000
    int* rowptr = (int*)(csr_w + 400000);    // 25,001
    int* cnt    = rowptr + 25024;            // 25,000
    int* cursor = cnt + 25024;               // 25,000
    int* csr_src = cursor + 25024;           // 400,000
    unsigned* pooled = (unsigned*)(csr_src + 400000);  // 185,000

    const int* src = ei;          // edge_index[0]
    const int* dst = ei + E;      // edge_index[1]

    k_init<<<(G * H + 255) / 256, 256, 0, stream>>>(cnt, cursor, pooled);
    k_deg<<<(E + 255) / 256, 256, 0, stream>>>(dst, cnt, E);
    k_dis<<<(N + 255) / 256, 256, 0, stream>>>(cnt, dis, N);
    k_scan<<<1, 1024, 0, stream>>>(cnt, rowptr, N);
    k_scatter<<<(E + 255) / 256, 256, 0, stream>>>(src, dst, dis, rowptr, cursor,
                                                   csr_src, csr_w, E);

    // layer 0: aggregate in 9-ch space, then GEMM + bias + BN + ReLU -> xcat col 0
    k_aggr0<<<(N * 16 + 255) / 256, 256, 0, stream>>>(x, dis, rowptr, csr_src, csr_w, xa, N);
    k_gemm<9><<<N / 8, 192, 0, stream>>>(xa, 9, W0, b0,
                                         gamma, beta, mean, var, xcat, 4 * H, N);

    // layers 1..3: GEMM -> tmp, then fused aggregate+bias+BN+ReLU -> xcat col l
    for (int l = 1; l < 4; ++l) {
        k_gemm<185><<<N / 8, 192, 0, stream>>>(xcat + (l - 1) * H, 4 * H,
                                               W_h + (l - 1) * H * H, nullptr,
                                               nullptr, nullptr, nullptr, nullptr,
                                               tmp, H, N);
        k_aggr_bn<<<N, 192, 0, stream>>>(tmp, dis, rowptr, csr_src, csr_w,
                                         b_h + (l - 1) * H,
                                         gamma + l * H, beta + l * H,
                                         mean + l * H, var + l * H,
                                         xcat + l * H, N);
    }

    // JumpingKnowledge cat -> linear (740 -> 185) + bias -> tmp
    k_gemm<740><<<N / 8, 192, 0, stream>>>(xcat, 4 * H, W_jk, b_jk,
                                           nullptr, nullptr, nullptr, nullptr,
                                           tmp, H, N);

    k_pool<<<N, 192, 0, stream>>>(tmp, batch, pooled, N);
    k_out<<<G, 64, 0, stream>>>(pooled, W_out, b_out, out, G);
}

// Round 3
// 399.975 us; speedup vs baseline: 4.1217x; 1.6191x over previous
//
#include <hip/hip_runtime.h>
#include <hip/hip_bf16.h>

#define N_NODES 25000
#define N_EDGES 400000
#define N_GRAPHS 1000
#define HID 185
#define EPS 1e-5f
#define XPITCH 768            // xcat row pitch (4 * 192), bf16
#define APITCH 56             // LDS row pitch in shorts (112B: 16B-aligned, 2-way banks)

typedef __attribute__((ext_vector_type(8))) short bf16x8;
typedef __attribute__((ext_vector_type(4))) float f32x4;

__device__ __forceinline__ short f2bf(float f) {
    union { float f; unsigned u; } v; v.f = f;
    unsigned r = v.u + 0x7FFFu + ((v.u >> 16) & 1u);   // RNE
    return (short)(r >> 16);
}
__device__ __forceinline__ float bf2f(short s) {
    union { unsigned u; float f; } v; v.u = ((unsigned)(unsigned short)s) << 16;
    return v.f;
}

// ---- init ------------------------------------------------------------------
__global__ void k_init(int* cnt, int* cursor, unsigned* pooled) {
    int i = blockIdx.x * blockDim.x + threadIdx.x;
    if (i < N_NODES) { cnt[i] = 0; cursor[i] = 0; }
    if (i < N_GRAPHS * HID) pooled[i] = 0u;
}

__global__ void k_deg(const int* __restrict__ dst, int* cnt, int E) {
    int i = blockIdx.x * blockDim.x + threadIdx.x;
    if (i < E) atomicAdd(&cnt[dst[i]], 1);
}

__global__ void k_dis(const int* __restrict__ cnt, float* dis, int N) {
    int i = blockIdx.x * blockDim.x + threadIdx.x;
    if (i < N) dis[i] = rsqrtf((float)(cnt[i] + 1));
}

// ---- 3-phase exclusive scan of cnt -> rowptr -------------------------------
__global__ __launch_bounds__(256) void k_scan_part(const int* __restrict__ cnt,
                                                   int* __restrict__ bsum, int N) {
    int i = blockIdx.x * 256 + threadIdx.x;
    int v = (i < N) ? cnt[i] : 0;
    #pragma unroll
    for (int off = 32; off; off >>= 1) v += __shfl_down(v, off);
    __shared__ int s[4];
    if ((threadIdx.x & 63) == 0) s[threadIdx.x >> 6] = v;
    __syncthreads();
    if (threadIdx.x == 0) bsum[blockIdx.x] = s[0] + s[1] + s[2] + s[3];
}

__global__ __launch_bounds__(128) void k_scan_mid(const int* __restrict__ bsum,
                                                  int* __restrict__ boff, int NB) {
    __shared__ int s[128];
    int t = threadIdx.x;
    int v = (t < NB) ? bsum[t] : 0;
    s[t] = v; __syncthreads();
    for (int off = 1; off < 128; off <<= 1) {
        int x = (t >= off) ? s[t - off] : 0;
        __syncthreads();
        s[t] += x;
        __syncthreads();
    }
    if (t < NB) boff[t] = s[t] - v;
}

__global__ __launch_bounds__(256) void k_scan_add(const int* __restrict__ cnt,
                                                  const int* __restrict__ boff,
                                                  int* __restrict__ rowptr, int N) {
    __shared__ int s[256];
    int t = threadIdx.x;
    int i = blockIdx.x * 256 + t;
    int v = (i < N) ? cnt[i] : 0;
    s[t] = v; __syncthreads();
    for (int off = 1; off < 256; off <<= 1) {
        int x = (t >= off) ? s[t - off] : 0;
        __syncthreads();
        s[t] += x;
        __syncthreads();
    }
    if (i < N) rowptr[i + 1] = boff[blockIdx.x] + s[t];
    if (i == 0) rowptr[0] = 0;
}

__global__ void k_scatter(const int* __restrict__ src, const int* __restrict__ dst,
                          const float* __restrict__ dis, const int* __restrict__ rowptr,
                          int* cursor, int* __restrict__ csr_src,
                          float* __restrict__ csr_w, int E) {
    int e = blockIdx.x * blockDim.x + threadIdx.x;
    if (e < E) {
        int d = dst[e];
        int s = src[e];
        int pos = atomicAdd(&cursor[d], 1);
        int o = rowptr[d] + pos;
        csr_src[o] = s;
        csr_w[o] = dis[s];
    }
}

// ---- weight prep: transpose/pad/bf16 ---------------------------------------
// Wt_h[l][n(192)][k(192)], Wt_jk[n(192)][kk(768)] with kk = l*192 + j
__global__ void k_prep_w(const float* __restrict__ W_h, const float* __restrict__ W_jk,
                         short* __restrict__ Wt_h, short* __restrict__ Wt_jk) {
    int idx = blockIdx.x * 256 + threadIdx.x;
    const int HW = 3 * 192 * 192;
    if (idx < HW) {
        int l = idx / (192 * 192);
        int r = idx % (192 * 192);
        int n = r / 192, k = r % 192;
        float v = (n < HID && k < HID) ? W_h[(l * HID + k) * HID + n] : 0.0f;
        Wt_h[idx] = f2bf(v);
    } else if (idx < HW + 192 * 768) {
        int j2 = idx - HW;
        int n = j2 / 768, kk = j2 % 768;
        int l = kk / 192, j = kk % 192;
        float v = (n < HID && j < HID) ? W_jk[(l * HID + j) * HID + n] : 0.0f;
        Wt_jk[j2] = f2bf(v);
    }
}

// ---- layer-0 aggregation in 9-ch input space -------------------------------
__global__ void k_aggr0(const float* __restrict__ x, const float* __restrict__ dis,
                        const int* __restrict__ rowptr, const int* __restrict__ csr_src,
                        const float* __restrict__ csr_w, float* __restrict__ xa, int N) {
    int idx = blockIdx.x * blockDim.x + threadIdx.x;
    int n = idx >> 4;
    int c = idx & 15;
    if (n >= N || c >= 9) return;
    float dn = dis[n];
    float acc = x[n * 9 + c] * dn;
    int beg = rowptr[n], end = rowptr[n + 1];
    for (int e = beg; e < end; ++e)
        acc += x[csr_src[e] * 9 + c] * csr_w[e];
    xa[n * 9 + c] = acc * dn;
}

// ---- layer-0 GEMM (fp32 vector, K=9) + bias + BN + ReLU -> bf16 xcat slice 0
__global__ __launch_bounds__(192) void k_gemm0(const float* __restrict__ A,
                                               const float* __restrict__ W,
                                               const float* __restrict__ bias,
                                               const float* __restrict__ gamma,
                                               const float* __restrict__ beta,
                                               const float* __restrict__ mean,
                                               const float* __restrict__ var,
                                               short* __restrict__ xcat, int N) {
    __shared__ float As[8 * 9];
    const int tid = threadIdx.x;
    const int r0 = blockIdx.x * 8;
    for (int idx = tid; idx < 72; idx += 192) {
        int r = idx & 7, k = idx >> 3;
        int row = r0 + r;
        As[idx] = (row < N) ? A[row * 9 + k] : 0.0f;
    }
    __syncthreads();
    const int c = tid;   // 0..191
    float res[8];
    #pragma unroll
    for (int r = 0; r < 8; ++r) res[r] = 0.0f;
    if (c < HID) {
        float acc[8] = {0,0,0,0,0,0,0,0};
        for (int k = 0; k < 9; ++k) {
            float w = W[k * HID + c];
            #pragma unroll
            for (int r = 0; r < 8; ++r) acc[r] += As[k * 8 + r] * w;
        }
        float scale = rsqrtf(var[c] + EPS) * gamma[c];
        float shift = beta[c] - mean[c] * scale;
        float bb = bias[c];
        #pragma unroll
        for (int r = 0; r < 8; ++r)
            res[r] = fmaxf((acc[r] + bb) * scale + shift, 0.0f);
    }
    #pragma unroll
    for (int r = 0; r < 8; ++r) {
        int row = r0 + r;
        if (row < N) xcat[row * XPITCH + c] = (c < HID) ? f2bf(res[r]) : (short)0;
    }
}

// ---- bf16 MFMA GEMM: C[N x 192] = A[N x KCH*32] @ Bt^T --------------------
// A: bf16, row pitch XPITCH (xcat). Bt: [192 n][KCH*32 k] bf16.
// Block: 256 thr (4 waves), 64 rows x 192 cols; wave w -> cols [w*48, w*48+48).
template<int KCH, bool F32OUT>
__global__ __launch_bounds__(256) void k_mgemm(const short* __restrict__ A,
                                               const short* __restrict__ Bt,
                                               const float* __restrict__ bias,
                                               void* __restrict__ Cout, int N) {
    __shared__ short As[64 * APITCH];
    __shared__ short Bs[192 * APITCH];
    const int tid = threadIdx.x;
    const int wave = tid >> 6;
    const int lane = tid & 63;
    const int quad = lane >> 4;
    const int lm = lane & 15;
    const int r0 = blockIdx.x * 64;
    const int KTOT = KCH * 32;
    const int arow = tid >> 2, aseg = tid & 3;

    f32x4 acc[4][3];
    #pragma unroll
    for (int i = 0; i < 4; ++i)
        #pragma unroll
        for (int j = 0; j < 3; ++j) acc[i][j] = (f32x4){0.f, 0.f, 0.f, 0.f};

    for (int kc = 0; kc < KCH; ++kc) {
        const int k0 = kc * 32;
        {   // stage A: 64 rows x 32 k (16B per thread)
            int grow = r0 + arow;
            bf16x8 v = (bf16x8){0,0,0,0,0,0,0,0};
            if (grow < N) v = *(const bf16x8*)(A + grow * XPITCH + k0 + aseg * 8);
            *(bf16x8*)(As + arow * APITCH + aseg * 8) = v;
        }
        #pragma unroll
        for (int i = 0; i < 3; ++i) {   // stage B: 192 rows x 32 k
            int u = tid + i * 256;
            int n = u >> 2, seg = u & 3;
            bf16x8 v = *(const bf16x8*)(Bt + n * KTOT + k0 + seg * 8);
            *(bf16x8*)(Bs + n * APITCH + seg * 8) = v;
        }
        __syncthreads();
        bf16x8 a[4], b[3];
        #pragma unroll
        for (int mt = 0; mt < 4; ++mt)
            a[mt] = *(const bf16x8*)(As + (mt * 16 + lm) * APITCH + quad * 8);
        #pragma unroll
        for (int nt = 0; nt < 3; ++nt)
            b[nt] = *(const bf16x8*)(Bs + (wave * 48 + nt * 16 + lm) * APITCH + quad * 8);
        #pragma unroll
        for (int mt = 0; mt < 4; ++mt)
            #pragma unroll
            for (int nt = 0; nt < 3; ++nt)
                acc[mt][nt] = __builtin_amdgcn_mfma_f32_16x16x32_bf16(a[mt], b[nt], acc[mt][nt], 0, 0, 0);
        __syncthreads();
    }
    // epilogue: D[row][col], col = lane&15 (+tile), row = quad*4 + reg (+tile)
    #pragma unroll
    for (int mt = 0; mt < 4; ++mt) {
        #pragma unroll
        for (int nt = 0; nt < 3; ++nt) {
            int col = wave * 48 + nt * 16 + lm;
            #pragma unroll
            for (int r = 0; r < 4; ++r) {
                int row = r0 + mt * 16 + quad * 4 + r;
                if (row < N) {
                    float v = acc[mt][nt][r];
                    if (F32OUT) {
                        float bb = (col < HID) ? bias[col] : 0.0f;
                        ((float*)Cout)[row * 192 + col] = v + bb;
                    } else {
                        ((short*)Cout)[row * 192 + col] = f2bf(v);
                    }
                }
            }
        }
    }
}

// ---- fused aggregation + bias + BN + ReLU (layers 1..3), bf16 in/out -------
__global__ __launch_bounds__(192) void k_aggr_bn(const short* __restrict__ tmp16,
                                                 const float* __restrict__ dis,
                                                 const int* __restrict__ rowptr,
                                                 const int* __restrict__ csr_src,
                                                 const float* __restrict__ csr_w,
                                                 const float* __restrict__ b,
                                                 const float* __restrict__ gamma,
                                                 const float* __restrict__ beta,
                                                 const float* __restrict__ mean,
                                                 const float* __restrict__ var,
                                                 short* __restrict__ out, int N) {
    int n = blockIdx.x;
    int c = threadIdx.x;   // 0..191
    short outv = 0;
    if (c < HID) {
        int beg = rowptr[n], end = rowptr[n + 1];
        float dn = dis[n];
        float acc = bf2f(tmp16[n * 192 + c]) * dn;
        int e = beg;
        for (; e + 1 < end; e += 2) {
            int s0 = csr_src[e];
            int s1 = csr_src[e + 1];
            float w0 = csr_w[e];
            float w1 = csr_w[e + 1];
            acc += bf2f(tmp16[s0 * 192 + c]) * w0;
            acc += bf2f(tmp16[s1 * 192 + c]) * w1;
        }
        if (e < end)
            acc += bf2f(tmp16[csr_src[e] * 192 + c]) * csr_w[e];
        acc = acc * dn + b[c];
        float scale = rsqrtf(var[c] + EPS) * gamma[c];
        float v = (acc - mean[c]) * scale + beta[c];
        outv = f2bf(fmaxf(v, 0.0f));
    }
    out[n * XPITCH + c] = outv;
}

// ---- global max pool -------------------------------------------------------
__global__ __launch_bounds__(192) void k_pool(const float* __restrict__ h,
                                              const int* __restrict__ batch,
                                              unsigned* __restrict__ pooled, int N) {
    int n = blockIdx.x;
    int g = batch[n];
    int c = threadIdx.x;
    if (c < HID) {
        unsigned b = __float_as_uint(h[n * 192 + c]);
        unsigned enc = (b & 0x80000000u) ? ~b : (b | 0x80000000u);
        atomicMax(&pooled[g * HID + c], enc);
    }
}

__global__ __launch_bounds__(64) void k_out(const unsigned* __restrict__ pooled,
                                            const float* __restrict__ W_out,
                                            const float* __restrict__ b_out,
                                            float* __restrict__ out, int G) {
    int g = blockIdx.x;
    int lane = threadIdx.x;
    float sum = 0.0f;
    for (int c = lane; c < HID; c += 64) {
        unsigned u = pooled[g * HID + c];
        unsigned bits = (u & 0x80000000u) ? (u & 0x7FFFFFFFu) : ~u;
        sum += __uint_as_float(bits) * W_out[c];
    }
    #pragma unroll
    for (int off = 32; off; off >>= 1) sum += __shfl_down(sum, off);
    if (lane == 0) out[g] = sum + b_out[0];
}

extern "C" void kernel_launch(void* const* d_in, const int* in_sizes, int n_in,
                              void* d_out, int out_size, void* d_ws, size_t ws_size,
                              hipStream_t stream) {
    const float* x      = (const float*)d_in[0];
    const int*   ei     = (const int*)  d_in[1];
    const int*   batch  = (const int*)  d_in[2];
    const float* W0     = (const float*)d_in[3];
    const float* b0     = (const float*)d_in[4];
    const float* W_h    = (const float*)d_in[5];
    const float* b_h    = (const float*)d_in[6];
    const float* gamma  = (const float*)d_in[7];
    const float* beta   = (const float*)d_in[8];
    const float* mean   = (const float*)d_in[9];
    const float* var    = (const float*)d_in[10];
    const float* W_jk   = (const float*)d_in[11];
    const float* b_jk   = (const float*)d_in[12];
    const float* W_out  = (const float*)d_in[13];
    const float* b_out  = (const float*)d_in[14];
    float* out = (float*)d_out;

    const int N = N_NODES, E = N_EDGES, G = N_GRAPHS, H = HID;
    const int NB = (N + 255) / 256;   // 98

    // workspace layout (element counts padded to 64)
    float* dis   = (float*)d_ws;                    // 25,000 -> 25,024
    float* xa    = dis + 25024;                     // 225,000 -> 225,024
    float* tmpf  = xa + 225024;                     // 25,000*192 = 4,800,000
    float* csr_w = tmpf + 4800000;                  // 400,000
    short* xcat  = (short*)(csr_w + 400000);        // 25,000*768 = 19,200,000 shorts
    short* tmp16 = xcat + 19200000;                 // 4,800,000 shorts
    short* Wt_h  = tmp16 + 4800000;                 // 110,592 shorts
    short* Wt_jk = Wt_h + 110592;                   // 147,456 shorts
    int* rowptr  = (int*)(Wt_jk + 147456);          // 25,001 -> 25,024
    int* cnt     = rowptr + 25024;                  // 25,024
    int* cursor  = cnt + 25024;                     // 25,024
    int* csr_src = cursor + 25024;                  // 400,000
    int* bsum    = csr_src + 400000;                // 128
    int* boff    = bsum + 128;                      // 128
    unsigned* pooled = (unsigned*)(boff + 128);     // 185,000

    const int* src = ei;
    const int* dst = ei + E;

    k_init<<<(G * H + 255) / 256, 256, 0, stream>>>(cnt, cursor, pooled);
    k_deg<<<(E + 255) / 256, 256, 0, stream>>>(dst, cnt, E);
    k_dis<<<(N + 255) / 256, 256, 0, stream>>>(cnt, dis, N);
    k_scan_part<<<NB, 256, 0, stream>>>(cnt, bsum, N);
    k_scan_mid<<<1, 128, 0, stream>>>(bsum, boff, NB);
    k_scan_add<<<NB, 256, 0, stream>>>(cnt, boff, rowptr, N);
    k_scatter<<<(E + 255) / 256, 256, 0, stream>>>(src, dst, dis, rowptr, cursor,
                                                   csr_src, csr_w, E);
    k_prep_w<<<(3 * 192 * 192 + 192 * 768 + 255) / 256, 256, 0, stream>>>(W_h, W_jk, Wt_h, Wt_jk);

    // layer 0
    k_aggr0<<<(N * 16 + 255) / 256, 256, 0, stream>>>(x, dis, rowptr, csr_src, csr_w, xa, N);
    k_gemm0<<<(N + 7) / 8, 192, 0, stream>>>(xa, W0, b0, gamma, beta, mean, var, xcat, N);

    // layers 1..3
    const int MB = (N + 63) / 64;   // 391
    for (int l = 1; l < 4; ++l) {
        k_mgemm<6, false><<<MB, 256, 0, stream>>>(xcat + (l - 1) * 192,
                                                  Wt_h + (l - 1) * 192 * 192,
                                                  nullptr, tmp16, N);
        k_aggr_bn<<<N, 192, 0, stream>>>(tmp16, dis, rowptr, csr_src, csr_w,
                                         b_h + (l - 1) * H,
                                         gamma + l * H, beta + l * H,
                                         mean + l * H, var + l * H,
                                         xcat + l * 192, N);
    }

    // JK: [N x 768] @ [768 x 192] + bias -> f32 tmpf
    k_mgemm<24, true><<<MB, 256, 0, stream>>>(xcat, Wt_jk, b_jk, tmpf, N);

    k_pool<<<N, 192, 0, stream>>>(tmpf, batch, pooled, N);
    k_out<<<G, 64, 0, stream>>>(pooled, W_out, b_out, out, G);
}

// Round 4
// 349.757 us; speedup vs baseline: 4.7135x; 1.1436x over previous
//
#include <hip/hip_runtime.h>
#include <hip/hip_bf16.h>

#define N_NODES 25000
#define N_EDGES 400000
#define N_GRAPHS 1000
#define HID 185
#define EPS 1e-5f
#define XPITCH 768            // xcat row pitch (4 * 192), bf16
#define APITCH 56             // LDS row pitch in shorts (112B: 16B-aligned, 2-way banks)

typedef __attribute__((ext_vector_type(8))) short bf16x8;
typedef __attribute__((ext_vector_type(4))) float f32x4;

__device__ __forceinline__ short f2bf(float f) {
    union { float f; unsigned u; } v; v.f = f;
    unsigned r = v.u + 0x7FFFu + ((v.u >> 16) & 1u);   // RNE
    return (short)(r >> 16);
}
__device__ __forceinline__ float bfl(unsigned u) { return __uint_as_float(u << 16); }
__device__ __forceinline__ float bfh(unsigned u) { return __uint_as_float(u & 0xFFFF0000u); }
__device__ __forceinline__ unsigned pk2(float lo, float hi) {
    return (unsigned)(unsigned short)f2bf(lo) | ((unsigned)(unsigned short)f2bf(hi) << 16);
}

// ---- init ------------------------------------------------------------------
__global__ void k_init(int* cnt, int* cursor, unsigned* pooled) {
    int i = blockIdx.x * blockDim.x + threadIdx.x;
    if (i < N_NODES) { cnt[i] = 0; cursor[i] = 0; }
    if (i < N_GRAPHS * HID) pooled[i] = 0u;
}

__global__ void k_deg(const int* __restrict__ dst, int* cnt, int E) {
    int i = blockIdx.x * blockDim.x + threadIdx.x;
    if (i < E) atomicAdd(&cnt[dst[i]], 1);
}

__global__ void k_dis(const int* __restrict__ cnt, float* dis, int N) {
    int i = blockIdx.x * blockDim.x + threadIdx.x;
    if (i < N) dis[i] = rsqrtf((float)(cnt[i] + 1));
}

// ---- 3-phase exclusive scan of cnt -> rowptr -------------------------------
__global__ __launch_bounds__(256) void k_scan_part(const int* __restrict__ cnt,
                                                   int* __restrict__ bsum, int N) {
    int i = blockIdx.x * 256 + threadIdx.x;
    int v = (i < N) ? cnt[i] : 0;
    #pragma unroll
    for (int off = 32; off; off >>= 1) v += __shfl_down(v, off);
    __shared__ int s[4];
    if ((threadIdx.x & 63) == 0) s[threadIdx.x >> 6] = v;
    __syncthreads();
    if (threadIdx.x == 0) bsum[blockIdx.x] = s[0] + s[1] + s[2] + s[3];
}

__global__ __launch_bounds__(128) void k_scan_mid(const int* __restrict__ bsum,
                                                  int* __restrict__ boff, int NB) {
    __shared__ int s[128];
    int t = threadIdx.x;
    int v = (t < NB) ? bsum[t] : 0;
    s[t] = v; __syncthreads();
    for (int off = 1; off < 128; off <<= 1) {
        int x = (t >= off) ? s[t - off] : 0;
        __syncthreads();
        s[t] += x;
        __syncthreads();
    }
    if (t < NB) boff[t] = s[t] - v;
}

__global__ __launch_bounds__(256) void k_scan_add(const int* __restrict__ cnt,
                                                  const int* __restrict__ boff,
                                                  int* __restrict__ rowptr, int N) {
    __shared__ int s[256];
    int t = threadIdx.x;
    int i = blockIdx.x * 256 + t;
    int v = (i < N) ? cnt[i] : 0;
    s[t] = v; __syncthreads();
    for (int off = 1; off < 256; off <<= 1) {
        int x = (t >= off) ? s[t - off] : 0;
        __syncthreads();
        s[t] += x;
        __syncthreads();
    }
    if (i < N) rowptr[i + 1] = boff[blockIdx.x] + s[t];
    if (i == 0) rowptr[0] = 0;
}

__global__ void k_scatter(const int* __restrict__ src, const int* __restrict__ dst,
                          const float* __restrict__ dis, const int* __restrict__ rowptr,
                          int* cursor, int* __restrict__ csr_src,
                          float* __restrict__ csr_w, int E) {
    int e = blockIdx.x * blockDim.x + threadIdx.x;
    if (e < E) {
        int d = dst[e];
        int s = src[e];
        int pos = atomicAdd(&cursor[d], 1);
        int o = rowptr[d] + pos;
        csr_src[o] = s;
        csr_w[o] = dis[s];
    }
}

// ---- weight prep: transpose/pad/bf16 + BN scale/shift tables ---------------
// Wt_h[l][n(192)][k(192)], Wt_jk[n(192)][kk(768)], bnsc/bnsh[4][192]
__global__ void k_prep_w(const float* __restrict__ W_h, const float* __restrict__ W_jk,
                         const float* __restrict__ b0, const float* __restrict__ b_h,
                         const float* __restrict__ gamma, const float* __restrict__ beta,
                         const float* __restrict__ mean, const float* __restrict__ var,
                         short* __restrict__ Wt_h, short* __restrict__ Wt_jk,
                         float* __restrict__ bnsc, float* __restrict__ bnsh) {
    int idx = blockIdx.x * 256 + threadIdx.x;
    const int HW = 3 * 192 * 192;
    const int JW = 192 * 768;
    if (idx < HW) {
        int l = idx / (192 * 192);
        int r = idx % (192 * 192);
        int n = r / 192, k = r % 192;
        float v = (n < HID && k < HID) ? W_h[(l * HID + k) * HID + n] : 0.0f;
        Wt_h[idx] = f2bf(v);
    } else if (idx < HW + JW) {
        int j2 = idx - HW;
        int n = j2 / 768, kk = j2 % 768;
        int l = kk / 192, j = kk % 192;
        float v = (n < HID && j < HID) ? W_jk[(l * HID + j) * HID + n] : 0.0f;
        Wt_jk[j2] = f2bf(v);
    } else if (idx < HW + JW + 4 * 192) {
        int li = idx - HW - JW;
        int l = li / 192, c = li % 192;
        float sc = 0.0f, sh = 0.0f;
        if (c < HID) {
            float bb = (l == 0) ? b0[c] : b_h[(l - 1) * HID + c];
            sc = rsqrtf(var[l * HID + c] + EPS) * gamma[l * HID + c];
            sh = (bb - mean[l * HID + c]) * sc + beta[l * HID + c];
        }
        bnsc[li] = sc;
        bnsh[li] = sh;
    }
}

// ---- layer-0 aggregation in 9-ch input space (unroll-4) --------------------
__global__ void k_aggr0(const float* __restrict__ x, const float* __restrict__ dis,
                        const int* __restrict__ rowptr, const int* __restrict__ csr_src,
                        const float* __restrict__ csr_w, float* __restrict__ xa, int N) {
    int idx = blockIdx.x * blockDim.x + threadIdx.x;
    int n = idx >> 4;
    int c = idx & 15;
    if (n >= N || c >= 9) return;
    float dn = dis[n];
    float acc = x[n * 9 + c] * dn;
    int e = rowptr[n], end = rowptr[n + 1];
    for (; e + 4 <= end; e += 4) {
        int s0 = csr_src[e], s1 = csr_src[e + 1], s2 = csr_src[e + 2], s3 = csr_src[e + 3];
        float w0 = csr_w[e], w1 = csr_w[e + 1], w2 = csr_w[e + 2], w3 = csr_w[e + 3];
        float v0 = x[s0 * 9 + c], v1 = x[s1 * 9 + c], v2 = x[s2 * 9 + c], v3 = x[s3 * 9 + c];
        acc += v0 * w0 + v1 * w1 + v2 * w2 + v3 * w3;
    }
    for (; e < end; ++e)
        acc += x[csr_src[e] * 9 + c] * csr_w[e];
    xa[n * 9 + c] = acc * dn;
}

// ---- layer-0 GEMM (fp32 vector, K=9) + BN + ReLU -> bf16 xcat slice 0 ------
__global__ __launch_bounds__(192) void k_gemm0(const float* __restrict__ A,
                                               const float* __restrict__ W,
                                               const float* __restrict__ bnsc,
                                               const float* __restrict__ bnsh,
                                               short* __restrict__ xcat, int N) {
    __shared__ float As[8 * 9];
    const int tid = threadIdx.x;
    const int r0 = blockIdx.x * 8;
    for (int idx = tid; idx < 72; idx += 192) {
        int r = idx & 7, k = idx >> 3;
        int row = r0 + r;
        As[idx] = (row < N) ? A[row * 9 + k] : 0.0f;
    }
    __syncthreads();
    const int c = tid;   // 0..191
    float res[8];
    #pragma unroll
    for (int r = 0; r < 8; ++r) res[r] = 0.0f;
    if (c < HID) {
        float acc[8] = {0,0,0,0,0,0,0,0};
        for (int k = 0; k < 9; ++k) {
            float w = W[k * HID + c];
            #pragma unroll
            for (int r = 0; r < 8; ++r) acc[r] += As[k * 8 + r] * w;
        }
        float sc = bnsc[c], sh = bnsh[c];
        #pragma unroll
        for (int r = 0; r < 8; ++r)
            res[r] = fmaxf(acc[r] * sc + sh, 0.0f);
    }
    #pragma unroll
    for (int r = 0; r < 8; ++r) {
        int row = r0 + r;
        if (row < N) xcat[row * XPITCH + c] = (c < HID) ? f2bf(res[r]) : (short)0;
    }
}

// ---- bf16 MFMA GEMM: C[N x 192] = A[N x KCH*32] @ Bt^T --------------------
// POOL=false: write bf16 tmp16[N x 192]. POOL=true: +bias, encode, atomicMax
// into pooled (global max pool fused; C never materialized).
template<int KCH, bool POOL>
__global__ __launch_bounds__(256) void k_mgemm(const short* __restrict__ A,
                                               const short* __restrict__ Bt,
                                               const float* __restrict__ bias,
                                               short* __restrict__ Cout,
                                               const int* __restrict__ batch,
                                               unsigned* __restrict__ pooled, int N) {
    __shared__ short As[64 * APITCH];
    __shared__ short Bs[192 * APITCH];
    __shared__ int sb[64];
    const int tid = threadIdx.x;
    const int wave = tid >> 6;
    const int lane = tid & 63;
    const int quad = lane >> 4;
    const int lm = lane & 15;
    const int r0 = blockIdx.x * 64;
    const int KTOT = KCH * 32;
    const int arow = tid >> 2, aseg = tid & 3;

    if (POOL) {
        if (tid < 64) sb[tid] = (r0 + tid < N) ? batch[r0 + tid] : 0;
    }

    f32x4 acc[4][3];
    #pragma unroll
    for (int i = 0; i < 4; ++i)
        #pragma unroll
        for (int j = 0; j < 3; ++j) acc[i][j] = (f32x4){0.f, 0.f, 0.f, 0.f};

    for (int kc = 0; kc < KCH; ++kc) {
        const int k0 = kc * 32;
        {   // stage A: 64 rows x 32 k (16B per thread)
            int grow = r0 + arow;
            bf16x8 v = (bf16x8){0,0,0,0,0,0,0,0};
            if (grow < N) v = *(const bf16x8*)(A + grow * XPITCH + k0 + aseg * 8);
            *(bf16x8*)(As + arow * APITCH + aseg * 8) = v;
        }
        #pragma unroll
        for (int i = 0; i < 3; ++i) {   // stage B: 192 rows x 32 k
            int u = tid + i * 256;
            int n = u >> 2, seg = u & 3;
            bf16x8 v = *(const bf16x8*)(Bt + n * KTOT + k0 + seg * 8);
            *(bf16x8*)(Bs + n * APITCH + seg * 8) = v;
        }
        __syncthreads();
        bf16x8 a[4], b[3];
        #pragma unroll
        for (int mt = 0; mt < 4; ++mt)
            a[mt] = *(const bf16x8*)(As + (mt * 16 + lm) * APITCH + quad * 8);
        #pragma unroll
        for (int nt = 0; nt < 3; ++nt)
            b[nt] = *(const bf16x8*)(Bs + (wave * 48 + nt * 16 + lm) * APITCH + quad * 8);
        #pragma unroll
        for (int mt = 0; mt < 4; ++mt)
            #pragma unroll
            for (int nt = 0; nt < 3; ++nt)
                acc[mt][nt] = __builtin_amdgcn_mfma_f32_16x16x32_bf16(a[mt], b[nt], acc[mt][nt], 0, 0, 0);
        __syncthreads();
    }
    // epilogue: D[row][col], col = lane&15 (+tile), row = quad*4 + reg (+tile)
    #pragma unroll
    for (int mt = 0; mt < 4; ++mt) {
        #pragma unroll
        for (int nt = 0; nt < 3; ++nt) {
            int col = wave * 48 + nt * 16 + lm;
            if (POOL) {
                if (col < HID) {
                    float bb = bias[col];
                    #pragma unroll
                    for (int r = 0; r < 4; ++r) {
                        int lrow = mt * 16 + quad * 4 + r;
                        if (r0 + lrow < N) {
                            float v = acc[mt][nt][r] + bb;
                            unsigned b32 = __float_as_uint(v);
                            unsigned enc = (b32 & 0x80000000u) ? ~b32 : (b32 | 0x80000000u);
                            atomicMax(&pooled[sb[lrow] * HID + col], enc);
                        }
                    }
                }
            } else {
                #pragma unroll
                for (int r = 0; r < 4; ++r) {
                    int row = r0 + mt * 16 + quad * 4 + r;
                    if (row < N) Cout[row * 192 + col] = f2bf(acc[mt][nt][r]);
                }
            }
        }
    }
}

// ---- fused aggregation + BN + ReLU (layers 1..3) ---------------------------
// one node per wave; lane covers 4 channels (uint2 = 4 bf16), 48 active lanes
__global__ __launch_bounds__(256) void k_aggr_bn(const short* __restrict__ tmp16,
                                                 const float* __restrict__ dis,
                                                 const int* __restrict__ rowptr,
                                                 const int* __restrict__ csr_src,
                                                 const float* __restrict__ csr_w,
                                                 const float* __restrict__ bnsc,
                                                 const float* __restrict__ bnsh,
                                                 short* __restrict__ outp, int N) {
    int n = (blockIdx.x << 2) + (threadIdx.x >> 6);
    if (n >= N) return;
    int lane = threadIdx.x & 63;
    int c0 = (lane < 48) ? (lane << 2) : 0;
    float dn = dis[n];
    float a0, a1, a2, a3;
    {
        uint2 v = *(const uint2*)(tmp16 + (size_t)n * 192 + c0);
        a0 = bfl(v.x) * dn; a1 = bfh(v.x) * dn; a2 = bfl(v.y) * dn; a3 = bfh(v.y) * dn;
    }
    int e = rowptr[n], end = rowptr[n + 1];
    for (; e + 4 <= end; e += 4) {
        int s0 = csr_src[e], s1 = csr_src[e + 1], s2 = csr_src[e + 2], s3 = csr_src[e + 3];
        float w0 = csr_w[e], w1 = csr_w[e + 1], w2 = csr_w[e + 2], w3 = csr_w[e + 3];
        uint2 v0 = *(const uint2*)(tmp16 + (size_t)s0 * 192 + c0);
        uint2 v1 = *(const uint2*)(tmp16 + (size_t)s1 * 192 + c0);
        uint2 v2 = *(const uint2*)(tmp16 + (size_t)s2 * 192 + c0);
        uint2 v3 = *(const uint2*)(tmp16 + (size_t)s3 * 192 + c0);
        a0 += bfl(v0.x) * w0; a1 += bfh(v0.x) * w0; a2 += bfl(v0.y) * w0; a3 += bfh(v0.y) * w0;
        a0 += bfl(v1.x) * w1; a1 += bfh(v1.x) * w1; a2 += bfl(v1.y) * w1; a3 += bfh(v1.y) * w1;
        a0 += bfl(v2.x) * w2; a1 += bfh(v2.x) * w2; a2 += bfl(v2.y) * w2; a3 += bfh(v2.y) * w2;
        a0 += bfl(v3.x) * w3; a1 += bfh(v3.x) * w3; a2 += bfl(v3.y) * w3; a3 += bfh(v3.y) * w3;
    }
    for (; e < end; ++e) {
        int s = csr_src[e];
        float w = csr_w[e];
        uint2 v = *(const uint2*)(tmp16 + (size_t)s * 192 + c0);
        a0 += bfl(v.x) * w; a1 += bfh(v.x) * w; a2 += bfl(v.y) * w; a3 += bfh(v.y) * w;
    }
    float4 sc = *(const float4*)(bnsc + c0);
    float4 sh = *(const float4*)(bnsh + c0);
    float o0 = fmaxf(a0 * dn * sc.x + sh.x, 0.0f);
    float o1 = fmaxf(a1 * dn * sc.y + sh.y, 0.0f);
    float o2 = fmaxf(a2 * dn * sc.z + sh.z, 0.0f);
    float o3 = fmaxf(a3 * dn * sc.w + sh.w, 0.0f);
    if (lane < 48) {
        uint2 p;
        p.x = pk2(o0, o1);
        p.y = pk2(o2, o3);
        *(uint2*)(outp + (size_t)n * XPITCH + c0) = p;
    }
}

// ---- final dense: out[g] = dot(decode(pooled[g]), W_out) + b_out -----------
__global__ __launch_bounds__(64) void k_out(const unsigned* __restrict__ pooled,
                                            const float* __restrict__ W_out,
                                            const float* __restrict__ b_out,
                                            float* __restrict__ out, int G) {
    int g = blockIdx.x;
    int lane = threadIdx.x;
    float sum = 0.0f;
    for (int c = lane; c < HID; c += 64) {
        unsigned u = pooled[g * HID + c];
        unsigned bits = (u & 0x80000000u) ? (u & 0x7FFFFFFFu) : ~u;
        sum += __uint_as_float(bits) * W_out[c];
    }
    #pragma unroll
    for (int off = 32; off; off >>= 1) sum += __shfl_down(sum, off);
    if (lane == 0) out[g] = sum + b_out[0];
}

extern "C" void kernel_launch(void* const* d_in, const int* in_sizes, int n_in,
                              void* d_out, int out_size, void* d_ws, size_t ws_size,
                              hipStream_t stream) {
    const float* x      = (const float*)d_in[0];
    const int*   ei     = (const int*)  d_in[1];
    const int*   batch  = (const int*)  d_in[2];
    const float* W0     = (const float*)d_in[3];
    const float* b0     = (const float*)d_in[4];
    const float* W_h    = (const float*)d_in[5];
    const float* b_h    = (const float*)d_in[6];
    const float* gamma  = (const float*)d_in[7];
    const float* beta   = (const float*)d_in[8];
    const float* mean   = (const float*)d_in[9];
    const float* var    = (const float*)d_in[10];
    const float* W_jk   = (const float*)d_in[11];
    const float* b_jk   = (const float*)d_in[12];
    const float* W_out  = (const float*)d_in[13];
    const float* b_out  = (const float*)d_in[14];
    float* out = (float*)d_out;

    const int N = N_NODES, E = N_EDGES, G = N_GRAPHS, H = HID;
    const int NB = (N + 255) / 256;   // 98

    // workspace layout
    float* dis   = (float*)d_ws;                    // 25,024
    float* xa    = dis + 25024;                     // 225,024
    float* csr_w = xa + 225024;                     // 400,000
    float* bnsc  = csr_w + 400000;                  // 768
    float* bnsh  = bnsc + 768;                      // 768
    short* xcat  = (short*)(bnsh + 768);            // 25,000*768 = 19,200,000 shorts
    short* tmp16 = xcat + 19200000;                 // 4,800,000 shorts
    short* Wt_h  = tmp16 + 4800000;                 // 110,592 shorts
    short* Wt_jk = Wt_h + 110592;                   // 147,456 shorts
    int* rowptr  = (int*)(Wt_jk + 147456);          // 25,024
    int* cnt     = rowptr + 25024;                  // 25,024
    int* cursor  = cnt + 25024;                     // 25,024
    int* csr_src = cursor + 25024;                  // 400,000
    int* bsum    = csr_src + 400000;                // 128
    int* boff    = bsum + 128;                      // 128
    unsigned* pooled = (unsigned*)(boff + 128);     // 185,000

    const int* src = ei;
    const int* dst = ei + E;

    k_init<<<(G * H + 255) / 256, 256, 0, stream>>>(cnt, cursor, pooled);
    k_deg<<<(E + 255) / 256, 256, 0, stream>>>(dst, cnt, E);
    k_dis<<<(N + 255) / 256, 256, 0, stream>>>(cnt, dis, N);
    k_scan_part<<<NB, 256, 0, stream>>>(cnt, bsum, N);
    k_scan_mid<<<1, 128, 0, stream>>>(bsum, boff, NB);
    k_scan_add<<<NB, 256, 0, stream>>>(cnt, boff, rowptr, N);
    k_scatter<<<(E + 255) / 256, 256, 0, stream>>>(src, dst, dis, rowptr, cursor,
                                                   csr_src, csr_w, E);
    k_prep_w<<<(3 * 192 * 192 + 192 * 768 + 4 * 192 + 255) / 256, 256, 0, stream>>>(
        W_h, W_jk, b0, b_h, gamma, beta, mean, var, Wt_h, Wt_jk, bnsc, bnsh);

    // layer 0
    k_aggr0<<<(N * 16 + 255) / 256, 256, 0, stream>>>(x, dis, rowptr, csr_src, csr_w, xa, N);
    k_gemm0<<<(N + 7) / 8, 192, 0, stream>>>(xa, W0, bnsc, bnsh, xcat, N);

    // layers 1..3
    const int MB = (N + 63) / 64;   // 391
    for (int l = 1; l < 4; ++l) {
        k_mgemm<6, false><<<MB, 256, 0, stream>>>(xcat + (l - 1) * 192,
                                                  Wt_h + (l - 1) * 192 * 192,
                                                  nullptr, tmp16, nullptr, nullptr, N);
        k_aggr_bn<<<(N + 3) / 4, 256, 0, stream>>>(tmp16, dis, rowptr, csr_src, csr_w,
                                                   bnsc + l * 192, bnsh + l * 192,
                                                   xcat + l * 192, N);
    }

    // JK: [N x 768] @ [768 x 192] + bias, fused global-max-pool into pooled
    k_mgemm<24, true><<<MB, 256, 0, stream>>>(xcat, Wt_jk, b_jk, nullptr, batch, pooled, N);

    k_out<<<G, 64, 0, stream>>>(pooled, W_out, b_out, out, G);
}

// Round 5
// 315.840 us; speedup vs baseline: 5.2197x; 1.1074x over previous
//
#include <hip/hip_runtime.h>
#include <hip/hip_bf16.h>

#define N_NODES 25000
#define N_EDGES 400000
#define N_GRAPHS 1000
#define HID 185
#define EPS 1e-5f
#define XPITCH 768            // xcat row pitch (4 * 192), bf16
#define APITCH 36             // LDS row pitch in shorts (18 dwords; conflict-free quarter-wave)

typedef __attribute__((ext_vector_type(8))) short bf16x8;
typedef __attribute__((ext_vector_type(4))) float f32x4;

__device__ __forceinline__ short f2bf(float f) {
    union { float f; unsigned u; } v; v.f = f;
    unsigned r = v.u + 0x7FFFu + ((v.u >> 16) & 1u);   // RNE
    return (short)(r >> 16);
}
__device__ __forceinline__ float bfl(unsigned u) { return __uint_as_float(u << 16); }
__device__ __forceinline__ float bfh(unsigned u) { return __uint_as_float(u & 0xFFFF0000u); }
__device__ __forceinline__ unsigned pk2(float lo, float hi) {
    return (unsigned)(unsigned short)f2bf(lo) | ((unsigned)(unsigned short)f2bf(hi) << 16);
}

// ---- init ------------------------------------------------------------------
__global__ void k_init(int* cnt, int* cursor) {
    int i = blockIdx.x * blockDim.x + threadIdx.x;
    if (i < N_NODES) { cnt[i] = 0; cursor[i] = 0; }
}

__global__ void k_deg(const int* __restrict__ dst, int* cnt, int E) {
    int i = blockIdx.x * blockDim.x + threadIdx.x;
    if (i < E) atomicAdd(&cnt[dst[i]], 1);
}

__global__ void k_dis(const int* __restrict__ cnt, float* dis, int N) {
    int i = blockIdx.x * blockDim.x + threadIdx.x;
    if (i < N) dis[i] = rsqrtf((float)(cnt[i] + 1));
}

// ---- 3-phase exclusive scan of cnt -> rowptr -------------------------------
__global__ __launch_bounds__(256) void k_scan_part(const int* __restrict__ cnt,
                                                   int* __restrict__ bsum, int N) {
    int i = blockIdx.x * 256 + threadIdx.x;
    int v = (i < N) ? cnt[i] : 0;
    #pragma unroll
    for (int off = 32; off; off >>= 1) v += __shfl_down(v, off);
    __shared__ int s[4];
    if ((threadIdx.x & 63) == 0) s[threadIdx.x >> 6] = v;
    __syncthreads();
    if (threadIdx.x == 0) bsum[blockIdx.x] = s[0] + s[1] + s[2] + s[3];
}

__global__ __launch_bounds__(128) void k_scan_mid(const int* __restrict__ bsum,
                                                  int* __restrict__ boff, int NB) {
    __shared__ int s[128];
    int t = threadIdx.x;
    int v = (t < NB) ? bsum[t] : 0;
    s[t] = v; __syncthreads();
    for (int off = 1; off < 128; off <<= 1) {
        int x = (t >= off) ? s[t - off] : 0;
        __syncthreads();
        s[t] += x;
        __syncthreads();
    }
    if (t < NB) boff[t] = s[t] - v;
}

__global__ __launch_bounds__(256) void k_scan_add(const int* __restrict__ cnt,
                                                  const int* __restrict__ boff,
                                                  int* __restrict__ rowptr, int N) {
    __shared__ int s[256];
    int t = threadIdx.x;
    int i = blockIdx.x * 256 + t;
    int v = (i < N) ? cnt[i] : 0;
    s[t] = v; __syncthreads();
    for (int off = 1; off < 256; off <<= 1) {
        int x = (t >= off) ? s[t - off] : 0;
        __syncthreads();
        s[t] += x;
        __syncthreads();
    }
    if (i < N) rowptr[i + 1] = boff[blockIdx.x] + s[t];
    if (i == 0) rowptr[0] = 0;
}

__global__ void k_scatter(const int* __restrict__ src, const int* __restrict__ dst,
                          const float* __restrict__ dis, const int* __restrict__ rowptr,
                          int* cursor, int* __restrict__ csr_src,
                          float* __restrict__ csr_w, int E) {
    int e = blockIdx.x * blockDim.x + threadIdx.x;
    if (e < E) {
        int d = dst[e];
        int s = src[e];
        int pos = atomicAdd(&cursor[d], 1);
        int o = rowptr[d] + pos;
        csr_src[o] = s;
        csr_w[o] = dis[s];
    }
}

// ---- weight prep: transpose/pad/bf16 + BN scale/shift tables ---------------
__global__ void k_prep_w(const float* __restrict__ W_h, const float* __restrict__ W_jk,
                         const float* __restrict__ b0, const float* __restrict__ b_h,
                         const float* __restrict__ gamma, const float* __restrict__ beta,
                         const float* __restrict__ mean, const float* __restrict__ var,
                         short* __restrict__ Wt_h, short* __restrict__ Wt_jk,
                         float* __restrict__ bnsc, float* __restrict__ bnsh) {
    int idx = blockIdx.x * 256 + threadIdx.x;
    const int HW = 3 * 192 * 192;
    const int JW = 192 * 768;
    if (idx < HW) {
        int l = idx / (192 * 192);
        int r = idx % (192 * 192);
        int n = r / 192, k = r % 192;
        float v = (n < HID && k < HID) ? W_h[(l * HID + k) * HID + n] : 0.0f;
        Wt_h[idx] = f2bf(v);
    } else if (idx < HW + JW) {
        int j2 = idx - HW;
        int n = j2 / 768, kk = j2 % 768;
        int l = kk / 192, j = kk % 192;
        float v = (n < HID && j < HID) ? W_jk[(l * HID + j) * HID + n] : 0.0f;
        Wt_jk[j2] = f2bf(v);
    } else if (idx < HW + JW + 4 * 192) {
        int li = idx - HW - JW;
        int l = li / 192, c = li % 192;
        float sc = 0.0f, sh = 0.0f;
        if (c < HID) {
            float bb = (l == 0) ? b0[c] : b_h[(l - 1) * HID + c];
            sc = rsqrtf(var[l * HID + c] + EPS) * gamma[l * HID + c];
            sh = (bb - mean[l * HID + c]) * sc + beta[l * HID + c];
        }
        bnsc[li] = sc;
        bnsh[li] = sh;
    }
}

// ---- layer-0 aggregation in 9-ch input space (unroll-4) --------------------
__global__ void k_aggr0(const float* __restrict__ x, const float* __restrict__ dis,
                        const int* __restrict__ rowptr, const int* __restrict__ csr_src,
                        const float* __restrict__ csr_w, float* __restrict__ xa, int N) {
    int idx = blockIdx.x * blockDim.x + threadIdx.x;
    int n = idx >> 4;
    int c = idx & 15;
    if (n >= N || c >= 9) return;
    float dn = dis[n];
    float acc = x[n * 9 + c] * dn;
    int e = rowptr[n], end = rowptr[n + 1];
    for (; e + 4 <= end; e += 4) {
        int s0 = csr_src[e], s1 = csr_src[e + 1], s2 = csr_src[e + 2], s3 = csr_src[e + 3];
        float w0 = csr_w[e], w1 = csr_w[e + 1], w2 = csr_w[e + 2], w3 = csr_w[e + 3];
        float v0 = x[s0 * 9 + c], v1 = x[s1 * 9 + c], v2 = x[s2 * 9 + c], v3 = x[s3 * 9 + c];
        acc += v0 * w0 + v1 * w1 + v2 * w2 + v3 * w3;
    }
    for (; e < end; ++e)
        acc += x[csr_src[e] * 9 + c] * csr_w[e];
    xa[n * 9 + c] = acc * dn;
}

// ---- layer-0 GEMM (fp32 vector, K=9) + BN + ReLU -> bf16 xcat slice 0 ------
__global__ __launch_bounds__(192) void k_gemm0(const float* __restrict__ A,
                                               const float* __restrict__ W,
                                               const float* __restrict__ bnsc,
                                               const float* __restrict__ bnsh,
                                               short* __restrict__ xcat, int N) {
    __shared__ float As[8 * 9];
    const int tid = threadIdx.x;
    const int r0 = blockIdx.x * 8;
    for (int idx = tid; idx < 72; idx += 192) {
        int r = idx & 7, k = idx >> 3;
        int row = r0 + r;
        As[idx] = (row < N) ? A[row * 9 + k] : 0.0f;
    }
    __syncthreads();
    const int c = tid;   // 0..191
    float res[8];
    #pragma unroll
    for (int r = 0; r < 8; ++r) res[r] = 0.0f;
    if (c < HID) {
        float acc[8] = {0,0,0,0,0,0,0,0};
        for (int k = 0; k < 9; ++k) {
            float w = W[k * HID + c];
            #pragma unroll
            for (int r = 0; r < 8; ++r) acc[r] += As[k * 8 + r] * w;
        }
        float sc = bnsc[c], sh = bnsh[c];
        #pragma unroll
        for (int r = 0; r < 8; ++r)
            res[r] = fmaxf(acc[r] * sc + sh, 0.0f);
    }
    #pragma unroll
    for (int r = 0; r < 8; ++r) {
        int row = r0 + r;
        if (row < N) xcat[row * XPITCH + c] = (c < HID) ? f2bf(res[r]) : (short)0;
    }
}

// ---- bf16 MFMA GEMM: C[N x 192] = A[N x KCH*32] @ Bt^T --------------------
// F32OUT=false: write bf16 Cout[N x 192]. F32OUT=true: write f32 (no bias;
// bias folded into the pool kernel).
template<int KCH, bool F32OUT>
__global__ __launch_bounds__(256) void k_mgemm(const short* __restrict__ A,
                                               const short* __restrict__ Bt,
                                               void* __restrict__ Cout, int N) {
    __shared__ short As[64 * APITCH];
    __shared__ short Bs[192 * APITCH];
    const int tid = threadIdx.x;
    const int wave = tid >> 6;
    const int lane = tid & 63;
    const int quad = lane >> 4;
    const int lm = lane & 15;
    const int r0 = blockIdx.x * 64;
    const int KTOT = KCH * 32;
    const int arow = tid >> 2, aseg = tid & 3;

    f32x4 acc[4][3];
    #pragma unroll
    for (int i = 0; i < 4; ++i)
        #pragma unroll
        for (int j = 0; j < 3; ++j) acc[i][j] = (f32x4){0.f, 0.f, 0.f, 0.f};

    for (int kc = 0; kc < KCH; ++kc) {
        const int k0 = kc * 32;
        {   // stage A: 64 rows x 32 k (16B per thread)
            int grow = r0 + arow;
            bf16x8 v = (bf16x8){0,0,0,0,0,0,0,0};
            if (grow < N) v = *(const bf16x8*)(A + grow * XPITCH + k0 + aseg * 8);
            *(bf16x8*)(As + arow * APITCH + aseg * 8) = v;
        }
        #pragma unroll
        for (int i = 0; i < 3; ++i) {   // stage B: 192 rows x 32 k
            int u = tid + i * 256;
            int n = u >> 2, seg = u & 3;
            bf16x8 v = *(const bf16x8*)(Bt + n * KTOT + k0 + seg * 8);
            *(bf16x8*)(Bs + n * APITCH + seg * 8) = v;
        }
        __syncthreads();
        bf16x8 a[4], b[3];
        #pragma unroll
        for (int mt = 0; mt < 4; ++mt)
            a[mt] = *(const bf16x8*)(As + (mt * 16 + lm) * APITCH + quad * 8);
        #pragma unroll
        for (int nt = 0; nt < 3; ++nt)
            b[nt] = *(const bf16x8*)(Bs + (wave * 48 + nt * 16 + lm) * APITCH + quad * 8);
        #pragma unroll
        for (int mt = 0; mt < 4; ++mt)
            #pragma unroll
            for (int nt = 0; nt < 3; ++nt)
                acc[mt][nt] = __builtin_amdgcn_mfma_f32_16x16x32_bf16(a[mt], b[nt], acc[mt][nt], 0, 0, 0);
        __syncthreads();
    }
    // epilogue: D[row][col], col = lane&15 (+tile), row = quad*4 + reg (+tile)
    #pragma unroll
    for (int mt = 0; mt < 4; ++mt) {
        #pragma unroll
        for (int nt = 0; nt < 3; ++nt) {
            int col = wave * 48 + nt * 16 + lm;
            #pragma unroll
            for (int r = 0; r < 4; ++r) {
                int row = r0 + mt * 16 + quad * 4 + r;
                if (row < N) {
                    if (F32OUT) ((float*)Cout)[row * 192 + col] = acc[mt][nt][r];
                    else        ((short*)Cout)[row * 192 + col] = f2bf(acc[mt][nt][r]);
                }
            }
        }
    }
}

// ---- fused aggregation + BN + ReLU (layers 1..3) ---------------------------
// one node per wave; lane covers 4 channels (uint2 = 4 bf16), 48 active lanes
__global__ __launch_bounds__(256) void k_aggr_bn(const short* __restrict__ tmp16,
                                                 const float* __restrict__ dis,
                                                 const int* __restrict__ rowptr,
                                                 const int* __restrict__ csr_src,
                                                 const float* __restrict__ csr_w,
                                                 const float* __restrict__ bnsc,
                                                 const float* __restrict__ bnsh,
                                                 short* __restrict__ outp, int N) {
    int n = (blockIdx.x << 2) + (threadIdx.x >> 6);
    if (n >= N) return;
    int lane = threadIdx.x & 63;
    int c0 = (lane < 48) ? (lane << 2) : 0;
    float dn = dis[n];
    float a0, a1, a2, a3;
    {
        uint2 v = *(const uint2*)(tmp16 + (size_t)n * 192 + c0);
        a0 = bfl(v.x) * dn; a1 = bfh(v.x) * dn; a2 = bfl(v.y) * dn; a3 = bfh(v.y) * dn;
    }
    int e = rowptr[n], end = rowptr[n + 1];
    for (; e + 4 <= end; e += 4) {
        int s0 = csr_src[e], s1 = csr_src[e + 1], s2 = csr_src[e + 2], s3 = csr_src[e + 3];
        float w0 = csr_w[e], w1 = csr_w[e + 1], w2 = csr_w[e + 2], w3 = csr_w[e + 3];
        uint2 v0 = *(const uint2*)(tmp16 + (size_t)s0 * 192 + c0);
        uint2 v1 = *(const uint2*)(tmp16 + (size_t)s1 * 192 + c0);
        uint2 v2 = *(const uint2*)(tmp16 + (size_t)s2 * 192 + c0);
        uint2 v3 = *(const uint2*)(tmp16 + (size_t)s3 * 192 + c0);
        a0 += bfl(v0.x) * w0; a1 += bfh(v0.x) * w0; a2 += bfl(v0.y) * w0; a3 += bfh(v0.y) * w0;
        a0 += bfl(v1.x) * w1; a1 += bfh(v1.x) * w1; a2 += bfl(v1.y) * w1; a3 += bfh(v1.y) * w1;
        a0 += bfl(v2.x) * w2; a1 += bfh(v2.x) * w2; a2 += bfl(v2.y) * w2; a3 += bfh(v2.y) * w2;
        a0 += bfl(v3.x) * w3; a1 += bfh(v3.x) * w3; a2 += bfl(v3.y) * w3; a3 += bfh(v3.y) * w3;
    }
    for (; e < end; ++e) {
        int s = csr_src[e];
        float w = csr_w[e];
        uint2 v = *(const uint2*)(tmp16 + (size_t)s * 192 + c0);
        a0 += bfl(v.x) * w; a1 += bfh(v.x) * w; a2 += bfl(v.y) * w; a3 += bfh(v.y) * w;
    }
    float4 sc = *(const float4*)(bnsc + c0);
    float4 sh = *(const float4*)(bnsh + c0);
    float o0 = fmaxf(a0 * dn * sc.x + sh.x, 0.0f);
    float o1 = fmaxf(a1 * dn * sc.y + sh.y, 0.0f);
    float o2 = fmaxf(a2 * dn * sc.z + sh.z, 0.0f);
    float o3 = fmaxf(a3 * dn * sc.w + sh.w, 0.0f);
    if (lane < 48) {
        uint2 p;
        p.x = pk2(o0, o1);
        p.y = pk2(o2, o3);
        *(uint2*)(outp + (size_t)n * XPITCH + c0) = p;
    }
}

// ---- segmented global-max-pool + bias + final dense, one block per graph ---
// batch is sorted; block g binary-searches its node range [beg,end), takes a
// per-channel running max over coalesced rows of tmpf, then reduces
// dot(max + b_jk, W_out) + b_out -> out[g].  No atomics anywhere.
__global__ __launch_bounds__(192) void k_pool_out(const float* __restrict__ tmpf,
                                                  const int* __restrict__ batch,
                                                  const float* __restrict__ b_jk,
                                                  const float* __restrict__ W_out,
                                                  const float* __restrict__ b_out,
                                                  float* __restrict__ out, int N) {
    __shared__ int bounds[2];
    __shared__ float partial[3];
    const int g = blockIdx.x;
    const int tid = threadIdx.x;
    if (tid < 2) {
        int key = g + tid;              // lower_bound(batch, key)
        int lo = 0, hi = N;
        while (lo < hi) {
            int mid = (lo + hi) >> 1;
            if (batch[mid] < key) lo = mid + 1; else hi = mid;
        }
        bounds[tid] = lo;
    }
    __syncthreads();
    const int beg = bounds[0], end = bounds[1];
    float mx = -3.4e38f;
    for (int n = beg; n < end; ++n)
        mx = fmaxf(mx, tmpf[(size_t)n * 192 + tid]);
    float p = (tid < HID) ? (mx + b_jk[tid]) * W_out[tid] : 0.0f;
    #pragma unroll
    for (int off = 32; off; off >>= 1) p += __shfl_down(p, off);
    if ((tid & 63) == 0) partial[tid >> 6] = p;
    __syncthreads();
    if (tid == 0) out[g] = partial[0] + partial[1] + partial[2] + b_out[0];
}

extern "C" void kernel_launch(void* const* d_in, const int* in_sizes, int n_in,
                              void* d_out, int out_size, void* d_ws, size_t ws_size,
                              hipStream_t stream) {
    const float* x      = (const float*)d_in[0];
    const int*   ei     = (const int*)  d_in[1];
    const int*   batch  = (const int*)  d_in[2];
    const float* W0     = (const float*)d_in[3];
    const float* b0     = (const float*)d_in[4];
    const float* W_h    = (const float*)d_in[5];
    const float* b_h    = (const float*)d_in[6];
    const float* gamma  = (const float*)d_in[7];
    const float* beta   = (const float*)d_in[8];
    const float* mean   = (const float*)d_in[9];
    const float* var    = (const float*)d_in[10];
    const float* W_jk   = (const float*)d_in[11];
    const float* b_jk   = (const float*)d_in[12];
    const float* W_out  = (const float*)d_in[13];
    const float* b_out  = (const float*)d_in[14];
    float* out = (float*)d_out;

    const int N = N_NODES, E = N_EDGES, G = N_GRAPHS, H = HID;
    const int NB = (N + 255) / 256;   // 98

    // workspace layout
    float* dis   = (float*)d_ws;                    // 25,024
    float* xa    = dis + 25024;                     // 225,024
    float* csr_w = xa + 225024;                     // 400,000
    float* bnsc  = csr_w + 400000;                  // 768
    float* bnsh  = bnsc + 768;                      // 768
    float* tmpf  = bnsh + 768;                      // 4,800,000
    short* xcat  = (short*)(tmpf + 4800000);        // 19,200,000 shorts
    short* tmp16 = xcat + 19200000;                 // 4,800,000 shorts
    short* Wt_h  = tmp16 + 4800000;                 // 110,592 shorts
    short* Wt_jk = Wt_h + 110592;                   // 147,456 shorts
    int* rowptr  = (int*)(Wt_jk + 147456);          // 25,024
    int* cnt     = rowptr + 25024;                  // 25,024
    int* cursor  = cnt + 25024;                     // 25,024
    int* csr_src = cursor + 25024;                  // 400,000
    int* bsum    = csr_src + 400000;                // 128
    int* boff    = bsum + 128;                      // 128

    const int* src = ei;
    const int* dst = ei + E;

    k_init<<<NB, 256, 0, stream>>>(cnt, cursor);
    k_deg<<<(E + 255) / 256, 256, 0, stream>>>(dst, cnt, E);
    k_dis<<<NB, 256, 0, stream>>>(cnt, dis, N);
    k_scan_part<<<NB, 256, 0, stream>>>(cnt, bsum, N);
    k_scan_mid<<<1, 128, 0, stream>>>(bsum, boff, NB);
    k_scan_add<<<NB, 256, 0, stream>>>(cnt, boff, rowptr, N);
    k_scatter<<<(E + 255) / 256, 256, 0, stream>>>(src, dst, dis, rowptr, cursor,
                                                   csr_src, csr_w, E);
    k_prep_w<<<(3 * 192 * 192 + 192 * 768 + 4 * 192 + 255) / 256, 256, 0, stream>>>(
        W_h, W_jk, b0, b_h, gamma, beta, mean, var, Wt_h, Wt_jk, bnsc, bnsh);

    // layer 0
    k_aggr0<<<(N * 16 + 255) / 256, 256, 0, stream>>>(x, dis, rowptr, csr_src, csr_w, xa, N);
    k_gemm0<<<(N + 7) / 8, 192, 0, stream>>>(xa, W0, bnsc, bnsh, xcat, N);

    // layers 1..3
    const int MB = (N + 63) / 64;   // 391
    for (int l = 1; l < 4; ++l) {
        k_mgemm<6, false><<<MB, 256, 0, stream>>>(xcat + (l - 1) * 192,
                                                  Wt_h + (l - 1) * 192 * 192, tmp16, N);
        k_aggr_bn<<<(N + 3) / 4, 256, 0, stream>>>(tmp16, dis, rowptr, csr_src, csr_w,
                                                   bnsc + l * 192, bnsh + l * 192,
                                                   xcat + l * 192, N);
    }

    // JK: [N x 768] @ [768 x 192] -> f32 tmpf (bias folded into pool)
    k_mgemm<24, true><<<MB, 256, 0, stream>>>(xcat, Wt_jk, tmpf, N);

    // segmented max pool + bias + output dense, no atomics
    k_pool_out<<<G, 192, 0, stream>>>(tmpf, batch, b_jk, W_out, b_out, out, N);
}